// Round 3
// baseline (576.419 us; speedup 1.0000x reference)
//
#include <hip/hip_runtime.h>
#include <math.h>

#define B  32
#define U  4096
#define D  512     // D_DEC == D_ENC
#define H  4
#define HD 128
#define CK 31
#define CF 32
#define AU 512

#define BPB    32           // block-partials per batch row (U / 128 rows-per-block)
#define ROWS_W 32           // u-rows per wave

#define LOG2E 1.4426950408889634f

static __device__ __forceinline__ float readlane_f(float v, int l) {
    return __int_as_float(__builtin_amdgcn_readlane(__float_as_int(v), l));
}
static __device__ __forceinline__ float fast_exp2(float x) {
    return __builtin_amdgcn_exp2f(x);   // bare v_exp_f32 (2^x)
}

// ---------------- Kernel A: phi_s, v = Wpsi @ phi_s, ck = conv (x) Wloc ----
// ws_v / ws_const / ws_ck are pre-scaled by log2(e) so every softmax
// exponential downstream is a bare v_exp_f32 (2^x). softmax is exactly
// invariant: exp(x-m) == 2^((x-m)*log2e).
// Also zeroes outv (replaces a hipMemsetAsync dispatch) and the per-b
// last-block counters used by fused_pass1's folded combine.
__global__ __launch_bounds__(256) void prep_kernel(
    const float* __restrict__ dec,    // (B,512)
    const float* __restrict__ Wphi,   // (H,512,128)
    const float* __restrict__ bphi,   // (H,128)
    const float* __restrict__ Wpsi,   // (H,512,128)
    const float* __restrict__ bpsi,   // (H,128)
    const float* __restrict__ convk,  // (31,1,32)
    const float* __restrict__ Wloc,   // (32,4)
    float* __restrict__ ws_v,         // (B,H,512)   [scaled by log2e]
    float* __restrict__ ws_const,     // (B,H)       [scaled by log2e]
    float* __restrict__ ws_ck,        // (31,4)      [scaled by log2e]
    float* __restrict__ outv,         // (B,512) -> zeroed here
    int*   __restrict__ cnt)          // (B)     -> zeroed here
{
    __shared__ float decs[D];
    __shared__ float phis2[2][HD];
    __shared__ float phis[HD];
    const int b = blockIdx.x / H, h = blockIdx.x % H;
    const int tid = threadIdx.x;

    // zero outv slice for this (b,h) + counters (block 0)
    if (tid < 128) outv[(size_t)b * AU + h * 128 + tid] = 0.f;
    if (blockIdx.x == 0 && tid >= 128 && tid < 128 + B) cnt[tid - 128] = 0;

    for (int i = tid; i < D; i += 256) decs[i] = dec[b * D + i];
    __syncthreads();

    // phi projection with all 256 threads: split K in half
    {
        const int k = tid & 127, half = tid >> 7;
        const int d0 = half * 256;
        float acc = 0.f;
        const float* wp = Wphi + (size_t)h * D * HD + (size_t)d0 * HD + k;
        #pragma unroll 8
        for (int d = 0; d < 256; ++d) acc += decs[d0 + d] * wp[(size_t)d * HD];
        phis2[half][k] = acc;
    }
    __syncthreads();
    if (tid < HD) phis[tid] = phis2[0][tid] + phis2[1][tid] + bphi[h * HD + tid];
    __syncthreads();

    if (tid == 0) {
        float c = 0.f;
        for (int k = 0; k < HD; ++k) c += phis[k] * bpsi[h * HD + k];
        ws_const[b * H + h] = c * LOG2E;
    }

    // psi projection, float4-vectorized weight loads (16 B/lane)
    for (int e = tid; e < D; e += 256) {
        const float4* wq = (const float4*)(Wpsi + ((size_t)h * D + e) * HD);
        float acc = 0.f;
        #pragma unroll 8
        for (int k = 0; k < HD / 4; ++k) {
            float4 w = wq[k];
            acc += w.x * phis[4*k] + w.y * phis[4*k+1]
                 + w.z * phis[4*k+2] + w.w * phis[4*k+3];
        }
        ws_v[((size_t)b * H + h) * D + e] = acc * LOG2E;
    }

    if (blockIdx.x == 0 && tid < CK * H) {
        int t = tid / H, hh = tid % H;
        float acc = 0.f;
        for (int f = 0; f < CF; ++f) acc += convk[t * CF + f] * Wloc[f * H + hh];
        ws_ck[t * H + hh] = acc * LOG2E;
    }
}

// ---- Pass 1 (fused): energy + online-softmax partial context, ONE enc read
// + FOLDED COMBINE: the last block to finish for each b (device-scope
// atomic counter, threadfence release/acquire) merges the BPB partials into
// ctx[b] and MS[b] -- removes the separate combine launch and overlaps the
// merge with still-streaming blocks.
__global__ __launch_bounds__(256, 4) void fused_pass1(
    const float* __restrict__ enc,     // (B,U,512)
    const float* __restrict__ prevw,   // (B,U)
    const float* __restrict__ ws_v,    // (B,H,512)
    const float* __restrict__ ws_const,// (B,H)
    const float* __restrict__ ws_ck,   // (31,4)
    float* __restrict__ energy,        // (B,H,U)  [exp2 domain]
    float* __restrict__ pctx,          // (B,BPB,H,512)
    float* __restrict__ pms,           // (B,BPB,H,2)  m,s  [exp2 domain]
    float* __restrict__ ctx,           // (B,H,512)
    float* __restrict__ MS,            // (B,H,2)
    int*   __restrict__ cnt)           // (B) zeroed by prep
{
    const int b    = blockIdx.y;
    const int blk  = blockIdx.x;              // 0..BPB-1
    const int tid  = threadIdx.x;
    const int lane = tid & 63;
    const int wave = tid >> 6;
    const int ubase = (blk * 4 + wave) * ROWS_W;

    __shared__ float lctx[4][H][D];   // 32 KB
    __shared__ float lms[4][H][2];
    __shared__ float lalpha[H][4];
    // folded-combine scratch
    __shared__ float csm[H][BPB], css[H][BPB], csal[H][BPB];
    __shared__ float cMS[H][2];
    __shared__ int lastflag;

    // v fragments: lane owns d = lane*4..lane*4+3 and 256+lane*4..+3
    float4 v0[H], v1[H];
    #pragma unroll
    for (int h = 0; h < H; ++h) {
        const float* vp = ws_v + ((size_t)b * H + h) * D;
        v0[h] = *(const float4*)(vp + lane * 4);
        v1[h] = *(const float4*)(vp + 256 + lane * 4);
    }
    float ckr[H] = {0.f, 0.f, 0.f, 0.f};
    if (lane < CK) {
        #pragma unroll
        for (int h = 0; h < H; ++h) ckr[h] = ws_ck[lane * H + h];
    }
    float ct[H];
    #pragma unroll
    for (int h = 0; h < H; ++h) ct[h] = ws_const[b * H + h];

    // prevw window preload: row r, lane l needs prevw[ubase + r + l - 15],
    // and r + l <= 62 < 64, so one 64-lane register covers the whole strip.
    float w0;
    {
        const int gi = ubase - 15 + lane;
        w0 = (gi >= 0 && gi < U) ? prevw[b * U + gi] : 0.f;
    }

    float m0 = -3.402823466e38f, m1 = m0, m2 = m0, m3 = m0;
    float s0 = 0.f, s1 = 0.f, s2 = 0.f, s3 = 0.f;
    float4 z = {0.f, 0.f, 0.f, 0.f};
    float4 c00 = z, c01 = z, c10 = z, c11 = z, c20 = z, c21 = z, c30 = z, c31 = z;

    const bool b16 = (lane & 16) != 0;
    const bool b32 = (lane & 32) != 0;

    const float* encb = enc + ((size_t)b * U + ubase) * D;
    float4 e0 = *(const float4*)(encb + lane * 4);
    float4 e1 = *(const float4*)(encb + 256 + lane * 4);
    float4 n0 = *(const float4*)(encb + D + lane * 4);
    float4 n1 = *(const float4*)(encb + D + 256 + lane * 4);

    float* ep = energy + ((size_t)b * H + (lane < H ? lane : 0)) * U + ubase;

    for (int r = 0; r < ROWS_W; ++r) {
        float4 q0, q1;
        if (r < ROWS_W - 2) {
            const float* nx = encb + (size_t)(r + 2) * D;
            q0 = *(const float4*)(nx + lane * 4);
            q1 = *(const float4*)(nx + 256 + lane * 4);
        }
        // conv window value via cross-lane pull (no per-row global load)
        float pw = __int_as_float(
            __builtin_amdgcn_ds_bpermute((r + lane) << 2, __float_as_int(w0)));

        float p0 = pw * ckr[0]
            + e0.x*v0[0].x + e0.y*v0[0].y + e0.z*v0[0].z + e0.w*v0[0].w
            + e1.x*v1[0].x + e1.y*v1[0].y + e1.z*v1[0].z + e1.w*v1[0].w;
        float p1 = pw * ckr[1]
            + e0.x*v0[1].x + e0.y*v0[1].y + e0.z*v0[1].z + e0.w*v0[1].w
            + e1.x*v1[1].x + e1.y*v1[1].y + e1.z*v1[1].z + e1.w*v1[1].w;
        float p2 = pw * ckr[2]
            + e0.x*v0[2].x + e0.y*v0[2].y + e0.z*v0[2].z + e0.w*v0[2].w
            + e1.x*v1[2].x + e1.y*v1[2].y + e1.z*v1[2].z + e1.w*v1[2].w;
        float p3 = pw * ckr[3]
            + e0.x*v0[3].x + e0.y*v0[3].y + e0.z*v0[3].z + e0.w*v0[3].w
            + e1.x*v1[3].x + e1.y*v1[3].y + e1.z*v1[3].z + e1.w*v1[3].w;

        // ---- pairwise exchange reduce: group g of 16 lanes ends with head g
        float keepA = b16 ? p1 : p0, sendA = b16 ? p0 : p1;
        float a  = keepA + __shfl_xor(sendA, 16);
        float keepB = b16 ? p3 : p2, sendB = b16 ? p2 : p3;
        float bb = keepB + __shfl_xor(sendB, 16);
        float keepC = b32 ? bb : a, sendC = b32 ? a : bb;
        float c = keepC + __shfl_xor(sendC, 32);
        c += __shfl_xor(c, 1);
        c += __shfl_xor(c, 2);
        c += __shfl_xor(c, 4);
        c += __shfl_xor(c, 8);
        // wave-uniform broadcast via readlane (SGPR-resident)
        float eh0 = readlane_f(c, 0)  + ct[0];
        float eh1 = readlane_f(c, 16) + ct[1];
        float eh2 = readlane_f(c, 32) + ct[2];
        float eh3 = readlane_f(c, 48) + ct[3];

        if (lane < H) {
            float ev = (lane == 0) ? eh0 : (lane == 1) ? eh1 : (lane == 2) ? eh2 : eh3;
            ep[r] = ev;
        }

        // ---- online softmax update (wave-uniform branch), exp2 domain ----
        float mn0 = fmaxf(m0, eh0), mn1 = fmaxf(m1, eh1);
        float mn2 = fmaxf(m2, eh2), mn3 = fmaxf(m3, eh3);
        if (mn0 > m0 || mn1 > m1 || mn2 > m2 || mn3 > m3) {
            float a0 = fast_exp2(m0 - mn0), a1 = fast_exp2(m1 - mn1);
            float a2 = fast_exp2(m2 - mn2), a3 = fast_exp2(m3 - mn3);
            s0 *= a0; s1 *= a1; s2 *= a2; s3 *= a3;
            c00.x*=a0; c00.y*=a0; c00.z*=a0; c00.w*=a0; c01.x*=a0; c01.y*=a0; c01.z*=a0; c01.w*=a0;
            c10.x*=a1; c10.y*=a1; c10.z*=a1; c10.w*=a1; c11.x*=a1; c11.y*=a1; c11.z*=a1; c11.w*=a1;
            c20.x*=a2; c20.y*=a2; c20.z*=a2; c20.w*=a2; c21.x*=a2; c21.y*=a2; c21.z*=a2; c21.w*=a2;
            c30.x*=a3; c30.y*=a3; c30.z*=a3; c30.w*=a3; c31.x*=a3; c31.y*=a3; c31.z*=a3; c31.w*=a3;
            m0 = mn0; m1 = mn1; m2 = mn2; m3 = mn3;
        }
        float w0e = fast_exp2(eh0 - m0), w1e = fast_exp2(eh1 - m1);
        float w2e = fast_exp2(eh2 - m2), w3e = fast_exp2(eh3 - m3);
        s0 += w0e; s1 += w1e; s2 += w2e; s3 += w3e;
        c00.x += w0e*e0.x; c00.y += w0e*e0.y; c00.z += w0e*e0.z; c00.w += w0e*e0.w;
        c01.x += w0e*e1.x; c01.y += w0e*e1.y; c01.z += w0e*e1.z; c01.w += w0e*e1.w;
        c10.x += w1e*e0.x; c10.y += w1e*e0.y; c10.z += w1e*e0.z; c10.w += w1e*e0.w;
        c11.x += w1e*e1.x; c11.y += w1e*e1.y; c11.z += w1e*e1.z; c11.w += w1e*e1.w;
        c20.x += w2e*e0.x; c20.y += w2e*e0.y; c20.z += w2e*e0.z; c20.w += w2e*e0.w;
        c21.x += w2e*e1.x; c21.y += w2e*e1.y; c21.z += w2e*e1.z; c21.w += w2e*e1.w;
        c30.x += w3e*e0.x; c30.y += w3e*e0.y; c30.z += w3e*e0.z; c30.w += w3e*e0.w;
        c31.x += w3e*e1.x; c31.y += w3e*e1.y; c31.z += w3e*e1.z; c31.w += w3e*e1.w;

        e0 = n0; e1 = n1; n0 = q0; n1 = q1;
    }

    // ---- block-level merge of the 4 wave partials via LDS ----
    *(float4*)&lctx[wave][0][lane * 4]       = c00;
    *(float4*)&lctx[wave][0][256 + lane * 4] = c01;
    *(float4*)&lctx[wave][1][lane * 4]       = c10;
    *(float4*)&lctx[wave][1][256 + lane * 4] = c11;
    *(float4*)&lctx[wave][2][lane * 4]       = c20;
    *(float4*)&lctx[wave][2][256 + lane * 4] = c21;
    *(float4*)&lctx[wave][3][lane * 4]       = c30;
    *(float4*)&lctx[wave][3][256 + lane * 4] = c31;
    if (lane == 0) {
        lms[wave][0][0] = m0; lms[wave][0][1] = s0;
        lms[wave][1][0] = m1; lms[wave][1][1] = s1;
        lms[wave][2][0] = m2; lms[wave][2][1] = s2;
        lms[wave][3][0] = m3; lms[wave][3][1] = s3;
    }
    __syncthreads();

    const size_t pbase = ((size_t)(b * BPB + blk)) * H;
    if (tid < H) {
        const int h = tid;
        float M = fmaxf(fmaxf(lms[0][h][0], lms[1][h][0]),
                        fmaxf(lms[2][h][0], lms[3][h][0]));
        float S = 0.f;
        #pragma unroll
        for (int w = 0; w < 4; ++w) {
            float al = fast_exp2(lms[w][h][0] - M);
            lalpha[h][w] = al;
            S += al * lms[w][h][1];
        }
        pms[(pbase + h) * 2]     = M;
        pms[(pbase + h) * 2 + 1] = S;
    }
    __syncthreads();

    #pragma unroll
    for (int h = 0; h < H; ++h) {
        const float a0 = lalpha[h][0], a1 = lalpha[h][1];
        const float a2 = lalpha[h][2], a3 = lalpha[h][3];
        #pragma unroll
        for (int half = 0; half < 2; ++half) {
            const int d = tid + half * 256;
            float val = a0 * lctx[0][h][d] + a1 * lctx[1][h][d]
                      + a2 * lctx[2][h][d] + a3 * lctx[3][h][d];
            pctx[(pbase + h) * D + d] = val;
        }
    }

    // ---- folded combine: last block per b merges all BPB partials --------
    __threadfence();                       // release pctx/pms writes
    if (tid == 0) {
        int prev = atomicAdd(&cnt[b], 1);  // device-scope on CDNA
        lastflag = (prev == BPB - 1) ? 1 : 0;
    }
    __syncthreads();
    if (!lastflag) return;
    __threadfence();                       // acquire all writers' data

    if (tid < 128) {
        const int i = tid >> 2, h = tid & 3;
        csm[h][i] = pms[(((size_t)b * BPB + i) * H + h) * 2];
        css[h][i] = pms[(((size_t)b * BPB + i) * H + h) * 2 + 1];
    }
    __syncthreads();
    if (tid < H) {
        const int h = tid;
        float M = -3.402823466e38f;
        for (int i = 0; i < BPB; ++i) M = fmaxf(M, csm[h][i]);
        float S = 0.f;
        for (int i = 0; i < BPB; ++i) {
            float al = fast_exp2(csm[h][i] - M);
            csal[h][i] = al;
            S += al * css[h][i];
        }
        cMS[h][0] = M; cMS[h][1] = S;
        MS[(b * H + h) * 2]     = M;
        MS[(b * H + h) * 2 + 1] = S;
    }
    __syncthreads();

    #pragma unroll
    for (int h = 0; h < H; ++h) {
        const float iS = 1.0f / cMS[h][1];
        #pragma unroll
        for (int half = 0; half < 2; ++half) {
            const int d = tid + half * 256;
            float acc = 0.f;
            const float* pp = pctx + (((size_t)b * BPB) * H + h) * D + d;
            #pragma unroll 8
            for (int i = 0; i < BPB; ++i)
                acc += csal[h][i] * pp[(size_t)i * H * D];
            ctx[((size_t)b * H + h) * D + d] = acc * iS;
        }
    }
}

// ---- Tail: outproj + attw in ONE launch ----------------------------------
// grid (B, 32): y in [0,16) -> attw chunk; y in [16,32) -> outproj slice
// (j-half = (y-16)&1, k-chunk = (y-16)>>1). 1024 blocks, full chip.
__global__ __launch_bounds__(256) void tail_kernel(
    const float* __restrict__ energy,  // (B,H,U)  [exp2 domain]
    const float* __restrict__ MS,      // (B,H,2)
    const float* __restrict__ ctx,     // (B,H,512) = (B,2048)
    const float* __restrict__ Wout,    // (2048,512)
    const float* __restrict__ bout,    // (512)
    float* __restrict__ attw,          // (B,U)
    float* __restrict__ outv)          // (B,512) zeroed by prep
{
    const int b = blockIdx.x;
    const int role = blockIdx.y;
    const int tid = threadIdx.x;

    if (role < 16) {
        // attention_weights = mean_h softmax(energy)
        const int u = role * 256 + tid;
        float acc = 0.f;
        #pragma unroll
        for (int h = 0; h < H; ++h) {
            const float M  = MS[(b * H + h) * 2];
            const float iS = 1.0f / MS[(b * H + h) * 2 + 1];
            acc += fast_exp2(energy[((size_t)b * H + h) * U + u] - M) * iS;
        }
        attw[(size_t)b * U + u] = acc * 0.25f;
    } else {
        // outv[b, jh*256 + tid] += sum over k-chunk of ctx*Wout
        const int idx = role - 16;
        const int jh  = idx & 1;
        const int kc  = idx >> 1;           // 0..7
        const int j   = jh * 256 + tid;
        const int i0  = kc * 256;
        __shared__ float c_s[256];
        c_s[tid] = ctx[(size_t)b * (H * D) + i0 + tid];
        __syncthreads();

        float acc = (kc == 0) ? bout[j] : 0.f;
        #pragma unroll 8
        for (int i = 0; i < 256; ++i)
            acc += c_s[i] * Wout[(size_t)(i0 + i) * AU + j];
        atomicAdd(&outv[(size_t)b * AU + j], acc);
    }
}

extern "C" void kernel_launch(void* const* d_in, const int* in_sizes, int n_in,
                              void* d_out, int out_size, void* d_ws, size_t ws_size,
                              hipStream_t stream) {
    const float* dec   = (const float*)d_in[0];
    const float* enc   = (const float*)d_in[1];
    const float* prevw = (const float*)d_in[2];
    const float* Wphi  = (const float*)d_in[3];
    const float* bphi  = (const float*)d_in[4];
    const float* Wpsi  = (const float*)d_in[5];
    const float* bpsi  = (const float*)d_in[6];
    const float* convk = (const float*)d_in[7];
    const float* Wloc  = (const float*)d_in[8];
    const float* Wout  = (const float*)d_in[9];
    const float* bout  = (const float*)d_in[10];

    float* out  = (float*)d_out;
    float* outv = out;            // (B,512) context_vector
    float* attw = out + B * AU;   // (B,U) attention_weights

    float* ws        = (float*)d_ws;
    float* ws_v      = ws;                        // 65536
    float* ws_const  = ws + 65536;                // 128
    float* ws_ck     = ws + 65664;                // 124 (pad to 65792)
    float* ws_energy = ws + 65792;                // B*H*U = 524288
    float* ws_pctx   = ws_energy + (size_t)B*H*U;            // 2097152
    float* ws_pms    = ws_pctx + (size_t)B*BPB*H*D;          // 8192
    float* ws_MS     = ws_pms + (size_t)B*BPB*H*2;           // 256
    float* ws_ctx    = ws_MS + 256;                          // 65536
    int*   ws_cnt    = (int*)(ws_ctx + (size_t)B*H*D);       // B ints

    prep_kernel<<<dim3(B * H), 256, 0, stream>>>(dec, Wphi, bphi, Wpsi, bpsi,
                                                 convk, Wloc, ws_v, ws_const,
                                                 ws_ck, outv, ws_cnt);
    fused_pass1<<<dim3(BPB, B), 256, 0, stream>>>(enc, prevw, ws_v, ws_const,
                                                  ws_ck, ws_energy, ws_pctx,
                                                  ws_pms, ws_ctx, ws_MS, ws_cnt);
    tail_kernel<<<dim3(B, 32), 256, 0, stream>>>(ws_energy, ws_MS, ws_ctx,
                                                 Wout, bout, attw, outv);
}

// Round 5
// 429.673 us; speedup vs baseline: 1.3415x; 1.3415x over previous
//
#include <hip/hip_runtime.h>
#include <math.h>

#define B  32
#define U  4096
#define D  512     // D_DEC == D_ENC
#define H  4
#define HD 128
#define CK 31
#define CF 32
#define AU 512

#define BPB    32           // block-partials per batch row (U / 128 rows-per-block)
#define ROWS_W 32           // u-rows per wave

#define LOG2E 1.4426950408889634f

static __device__ __forceinline__ float readlane_f(float v, int l) {
    return __int_as_float(__builtin_amdgcn_readlane(__float_as_int(v), l));
}
static __device__ __forceinline__ float fast_exp2(float x) {
    return __builtin_amdgcn_exp2f(x);   // bare v_exp_f32 (2^x)
}

// ---------------- Kernel A: phi_s, v = Wpsi @ phi_s, ck = conv (x) Wloc ----
// ws_v / ws_const / ws_ck are pre-scaled by log2(e) so every softmax
// exponential downstream is a bare v_exp_f32 (2^x). softmax is exactly
// invariant: exp(x-m) == 2^((x-m)*log2e).
// Also zeroes outv (replaces a hipMemsetAsync dispatch).
__global__ __launch_bounds__(256) void prep_kernel(
    const float* __restrict__ dec,    // (B,512)
    const float* __restrict__ Wphi,   // (H,512,128)
    const float* __restrict__ bphi,   // (H,128)
    const float* __restrict__ Wpsi,   // (H,512,128)
    const float* __restrict__ bpsi,   // (H,128)
    const float* __restrict__ convk,  // (31,1,32)
    const float* __restrict__ Wloc,   // (32,4)
    float* __restrict__ ws_v,         // (B,H,512)   [scaled by log2e]
    float* __restrict__ ws_const,     // (B,H)       [scaled by log2e]
    float* __restrict__ ws_ck,        // (31,4)      [scaled by log2e]
    float* __restrict__ outv)         // (B,512) -> zeroed here
{
    __shared__ float decs[D];
    __shared__ float phis2[2][HD];
    __shared__ float phis[HD];
    const int b = blockIdx.x / H, h = blockIdx.x % H;
    const int tid = threadIdx.x;

    // zero outv slice for this (b,h)
    if (tid < 128) outv[(size_t)b * AU + h * 128 + tid] = 0.f;

    for (int i = tid; i < D; i += 256) decs[i] = dec[b * D + i];
    __syncthreads();

    // phi projection with all 256 threads: split K in half
    {
        const int k = tid & 127, half = tid >> 7;
        const int d0 = half * 256;
        float acc = 0.f;
        const float* wp = Wphi + (size_t)h * D * HD + (size_t)d0 * HD + k;
        #pragma unroll 8
        for (int d = 0; d < 256; ++d) acc += decs[d0 + d] * wp[(size_t)d * HD];
        phis2[half][k] = acc;
    }
    __syncthreads();
    if (tid < HD) phis[tid] = phis2[0][tid] + phis2[1][tid] + bphi[h * HD + tid];
    __syncthreads();

    if (tid == 0) {
        float c = 0.f;
        for (int k = 0; k < HD; ++k) c += phis[k] * bpsi[h * HD + k];
        ws_const[b * H + h] = c * LOG2E;
    }

    // psi projection, float4-vectorized weight loads (16 B/lane)
    for (int e = tid; e < D; e += 256) {
        const float4* wq = (const float4*)(Wpsi + ((size_t)h * D + e) * HD);
        float acc = 0.f;
        #pragma unroll 8
        for (int k = 0; k < HD / 4; ++k) {
            float4 w = wq[k];
            acc += w.x * phis[4*k] + w.y * phis[4*k+1]
                 + w.z * phis[4*k+2] + w.w * phis[4*k+3];
        }
        ws_v[((size_t)b * H + h) * D + e] = acc * LOG2E;
    }

    if (blockIdx.x == 0 && tid < CK * H) {
        int t = tid / H, hh = tid % H;
        float acc = 0.f;
        for (int f = 0; f < CF; ++f) acc += convk[t * CF + f] * Wloc[f * H + hh];
        ws_ck[t * H + hh] = acc * LOG2E;
    }
}

// ---- Pass 1 (fused): energy + online-softmax partial context, ONE enc read
// Block handles 128 u-rows (4 waves x 32); waves merge partials in LDS ->
// ONE (m,s,ctx) partial per block.
// REGISTER-PRESSURE NOTE (round-3 lesson): the loop's live set is ~110 VGPRs
// and __launch_bounds__(256,4) caps at 128. Round 3's folded-combine tail
// flipped the allocator to 64 VGPRs + spills -> pass1 went 3-6x slower
// (272us, VALUBusy 11%, HBM 7%). Do NOT add body code or prefetch depth
// here; 1-row lookahead measured identical to 2-row (BW-bound, not
// latency-starved).
__global__ __launch_bounds__(256, 4) void fused_pass1(
    const float* __restrict__ enc,     // (B,U,512)
    const float* __restrict__ prevw,   // (B,U)
    const float* __restrict__ ws_v,    // (B,H,512)
    const float* __restrict__ ws_const,// (B,H)
    const float* __restrict__ ws_ck,   // (31,4)
    float* __restrict__ energy,        // (B,H,U)  [exp2 domain]
    float* __restrict__ pctx,          // (B,BPB,H,512)
    float* __restrict__ pms)           // (B,BPB,H,2)  m,s  [exp2 domain]
{
    const int b    = blockIdx.y;
    const int blk  = blockIdx.x;              // 0..BPB-1
    const int tid  = threadIdx.x;
    const int lane = tid & 63;
    const int wave = tid >> 6;
    const int ubase = (blk * 4 + wave) * ROWS_W;

    __shared__ float lctx[4][H][D];   // 32 KB
    __shared__ float lms[4][H][2];
    __shared__ float lalpha[H][4];

    // v fragments: lane owns d = lane*4..lane*4+3 and 256+lane*4..+3
    float4 v0[H], v1[H];
    #pragma unroll
    for (int h = 0; h < H; ++h) {
        const float* vp = ws_v + ((size_t)b * H + h) * D;
        v0[h] = *(const float4*)(vp + lane * 4);
        v1[h] = *(const float4*)(vp + 256 + lane * 4);
    }
    float ckr[H] = {0.f, 0.f, 0.f, 0.f};
    if (lane < CK) {
        #pragma unroll
        for (int h = 0; h < H; ++h) ckr[h] = ws_ck[lane * H + h];
    }
    float ct[H];
    #pragma unroll
    for (int h = 0; h < H; ++h) ct[h] = ws_const[b * H + h];

    // prevw window preload: row r, lane l needs prevw[ubase + r + l - 15],
    // and r + l <= 62 < 64, so one 64-lane register covers the whole strip.
    float w0;
    {
        const int gi = ubase - 15 + lane;
        w0 = (gi >= 0 && gi < U) ? prevw[b * U + gi] : 0.f;
    }

    float m0 = -3.402823466e38f, m1 = m0, m2 = m0, m3 = m0;
    float s0 = 0.f, s1 = 0.f, s2 = 0.f, s3 = 0.f;
    float4 z = {0.f, 0.f, 0.f, 0.f};
    float4 c00 = z, c01 = z, c10 = z, c11 = z, c20 = z, c21 = z, c30 = z, c31 = z;

    const bool b16 = (lane & 16) != 0;
    const bool b32 = (lane & 32) != 0;

    const float* encb = enc + ((size_t)b * U + ubase) * D;
    float4 e0 = *(const float4*)(encb + lane * 4);
    float4 e1 = *(const float4*)(encb + 256 + lane * 4);

    for (int r = 0; r < ROWS_W; ++r) {
        float4 n0, n1;
        if (r < ROWS_W - 1) {
            const float* nx = encb + (size_t)(r + 1) * D;
            n0 = *(const float4*)(nx + lane * 4);
            n1 = *(const float4*)(nx + 256 + lane * 4);
        }
        const int u = ubase + r;
        // conv window value via cross-lane pull (no per-row global load)
        float pw = __int_as_float(
            __builtin_amdgcn_ds_bpermute((r + lane) << 2, __float_as_int(w0)));

        float p0 = pw * ckr[0]
            + e0.x*v0[0].x + e0.y*v0[0].y + e0.z*v0[0].z + e0.w*v0[0].w
            + e1.x*v1[0].x + e1.y*v1[0].y + e1.z*v1[0].z + e1.w*v1[0].w;
        float p1 = pw * ckr[1]
            + e0.x*v0[1].x + e0.y*v0[1].y + e0.z*v0[1].z + e0.w*v0[1].w
            + e1.x*v1[1].x + e1.y*v1[1].y + e1.z*v1[1].z + e1.w*v1[1].w;
        float p2 = pw * ckr[2]
            + e0.x*v0[2].x + e0.y*v0[2].y + e0.z*v0[2].z + e0.w*v0[2].w
            + e1.x*v1[2].x + e1.y*v1[2].y + e1.z*v1[2].z + e1.w*v1[2].w;
        float p3 = pw * ckr[3]
            + e0.x*v0[3].x + e0.y*v0[3].y + e0.z*v0[3].z + e0.w*v0[3].w
            + e1.x*v1[3].x + e1.y*v1[3].y + e1.z*v1[3].z + e1.w*v1[3].w;

        // ---- pairwise exchange reduce: group g of 16 lanes ends with head g
        float keepA = b16 ? p1 : p0, sendA = b16 ? p0 : p1;
        float a  = keepA + __shfl_xor(sendA, 16);
        float keepB = b16 ? p3 : p2, sendB = b16 ? p2 : p3;
        float bb = keepB + __shfl_xor(sendB, 16);
        float keepC = b32 ? bb : a, sendC = b32 ? a : bb;
        float c = keepC + __shfl_xor(sendC, 32);
        c += __shfl_xor(c, 1);
        c += __shfl_xor(c, 2);
        c += __shfl_xor(c, 4);
        c += __shfl_xor(c, 8);
        // wave-uniform broadcast via readlane (SGPR-resident)
        float eh0 = readlane_f(c, 0)  + ct[0];
        float eh1 = readlane_f(c, 16) + ct[1];
        float eh2 = readlane_f(c, 32) + ct[2];
        float eh3 = readlane_f(c, 48) + ct[3];

        if (lane < H) {
            float ev = (lane == 0) ? eh0 : (lane == 1) ? eh1 : (lane == 2) ? eh2 : eh3;
            energy[((size_t)b * H + lane) * U + u] = ev;
        }

        // ---- online softmax update (wave-uniform branch), exp2 domain ----
        float mn0 = fmaxf(m0, eh0), mn1 = fmaxf(m1, eh1);
        float mn2 = fmaxf(m2, eh2), mn3 = fmaxf(m3, eh3);
        if (mn0 > m0 || mn1 > m1 || mn2 > m2 || mn3 > m3) {
            float a0 = fast_exp2(m0 - mn0), a1 = fast_exp2(m1 - mn1);
            float a2 = fast_exp2(m2 - mn2), a3 = fast_exp2(m3 - mn3);
            s0 *= a0; s1 *= a1; s2 *= a2; s3 *= a3;
            c00.x*=a0; c00.y*=a0; c00.z*=a0; c00.w*=a0; c01.x*=a0; c01.y*=a0; c01.z*=a0; c01.w*=a0;
            c10.x*=a1; c10.y*=a1; c10.z*=a1; c10.w*=a1; c11.x*=a1; c11.y*=a1; c11.z*=a1; c11.w*=a1;
            c20.x*=a2; c20.y*=a2; c20.z*=a2; c20.w*=a2; c21.x*=a2; c21.y*=a2; c21.z*=a2; c21.w*=a2;
            c30.x*=a3; c30.y*=a3; c30.z*=a3; c30.w*=a3; c31.x*=a3; c31.y*=a3; c31.z*=a3; c31.w*=a3;
            m0 = mn0; m1 = mn1; m2 = mn2; m3 = mn3;
        }
        float w0e = fast_exp2(eh0 - m0), w1e = fast_exp2(eh1 - m1);
        float w2e = fast_exp2(eh2 - m2), w3e = fast_exp2(eh3 - m3);
        s0 += w0e; s1 += w1e; s2 += w2e; s3 += w3e;
        c00.x += w0e*e0.x; c00.y += w0e*e0.y; c00.z += w0e*e0.z; c00.w += w0e*e0.w;
        c01.x += w0e*e1.x; c01.y += w0e*e1.y; c01.z += w0e*e1.z; c01.w += w0e*e1.w;
        c10.x += w1e*e0.x; c10.y += w1e*e0.y; c10.z += w1e*e0.z; c10.w += w1e*e0.w;
        c11.x += w1e*e1.x; c11.y += w1e*e1.y; c11.z += w1e*e1.z; c11.w += w1e*e1.w;
        c20.x += w2e*e0.x; c20.y += w2e*e0.y; c20.z += w2e*e0.z; c20.w += w2e*e0.w;
        c21.x += w2e*e1.x; c21.y += w2e*e1.y; c21.z += w2e*e1.z; c21.w += w2e*e1.w;
        c30.x += w3e*e0.x; c30.y += w3e*e0.y; c30.z += w3e*e0.z; c30.w += w3e*e0.w;
        c31.x += w3e*e1.x; c31.y += w3e*e1.y; c31.z += w3e*e1.z; c31.w += w3e*e1.w;

        e0 = n0; e1 = n1;
    }

    // ---- block-level merge of the 4 wave partials via LDS ----
    *(float4*)&lctx[wave][0][lane * 4]       = c00;
    *(float4*)&lctx[wave][0][256 + lane * 4] = c01;
    *(float4*)&lctx[wave][1][lane * 4]       = c10;
    *(float4*)&lctx[wave][1][256 + lane * 4] = c11;
    *(float4*)&lctx[wave][2][lane * 4]       = c20;
    *(float4*)&lctx[wave][2][256 + lane * 4] = c21;
    *(float4*)&lctx[wave][3][lane * 4]       = c30;
    *(float4*)&lctx[wave][3][256 + lane * 4] = c31;
    if (lane == 0) {
        lms[wave][0][0] = m0; lms[wave][0][1] = s0;
        lms[wave][1][0] = m1; lms[wave][1][1] = s1;
        lms[wave][2][0] = m2; lms[wave][2][1] = s2;
        lms[wave][3][0] = m3; lms[wave][3][1] = s3;
    }
    __syncthreads();

    const size_t pbase = ((size_t)(b * BPB + blk)) * H;
    if (tid < H) {
        const int h = tid;
        float M = fmaxf(fmaxf(lms[0][h][0], lms[1][h][0]),
                        fmaxf(lms[2][h][0], lms[3][h][0]));
        float S = 0.f;
        #pragma unroll
        for (int w = 0; w < 4; ++w) {
            float al = fast_exp2(lms[w][h][0] - M);
            lalpha[h][w] = al;
            S += al * lms[w][h][1];
        }
        pms[(pbase + h) * 2]     = M;
        pms[(pbase + h) * 2 + 1] = S;
    }
    __syncthreads();

    #pragma unroll
    for (int h = 0; h < H; ++h) {
        const float a0 = lalpha[h][0], a1 = lalpha[h][1];
        const float a2 = lalpha[h][2], a3 = lalpha[h][3];
        #pragma unroll
        for (int half = 0; half < 2; ++half) {
            const int d = tid + half * 256;
            float val = a0 * lctx[0][h][d] + a1 * lctx[1][h][d]
                      + a2 * lctx[2][h][d] + a3 * lctx[3][h][d];
            pctx[(pbase + h) * D + d] = val;
        }
    }
}

// ---- Pass 2: combine per-block partials -> ctx (B,H,512), save M,S -------
// Light, 128 blocks. Kept as its own launch: folding it into pass1 (round 3)
// blew the VGPR budget and cost 141us.
__global__ __launch_bounds__(256) void combine_kernel(
    const float* __restrict__ pctx,  // (B,BPB,H,512)
    const float* __restrict__ pms,   // (B,BPB,H,2)
    float* __restrict__ ctx,         // (B,H,512)
    float* __restrict__ MS)          // (B,H,2)
{
    const int bh = blockIdx.x;       // b*H+h
    const int b = bh >> 2, h = bh & 3;
    const int tid = threadIdx.x;
    __shared__ float sm[BPB], ss[BPB], salpha[BPB];
    __shared__ float MSsh[2];

    if (tid < BPB) {
        sm[tid] = pms[(((size_t)b * BPB + tid) * H + h) * 2];
        ss[tid] = pms[(((size_t)b * BPB + tid) * H + h) * 2 + 1];
    }
    __syncthreads();
    if (tid == 0) {
        float M = -3.402823466e38f;
        for (int i = 0; i < BPB; ++i) M = fmaxf(M, sm[i]);
        float S = 0.f;
        for (int i = 0; i < BPB; ++i) {
            float al = fast_exp2(sm[i] - M);
            salpha[i] = al;
            S += al * ss[i];
        }
        MSsh[0] = M; MSsh[1] = S;
        MS[bh * 2] = M; MS[bh * 2 + 1] = S;
    }
    __syncthreads();
    const float invS = 1.0f / MSsh[1];

    float acc0 = 0.f, acc1 = 0.f;
    const float* base = pctx + ((size_t)b * BPB * H + h) * D;
    #pragma unroll 4
    for (int i = 0; i < BPB; ++i) {
        float al = salpha[i];
        const float* p = base + (size_t)i * H * D;
        acc0 += al * p[tid];
        acc1 += al * p[tid + 256];
    }
    ctx[(size_t)bh * D + tid]       = acc0 * invS;
    ctx[(size_t)bh * D + tid + 256] = acc1 * invS;
}

// ---- Tail: outproj + attw in ONE launch ----------------------------------
// grid (B, 32): y in [0,16) -> attw chunk; y in [16,32) -> outproj slice
// (j-half = (y-16)&1, k-chunk = (y-16)>>1). 1024 blocks, full chip.
__global__ __launch_bounds__(256) void tail_kernel(
    const float* __restrict__ energy,  // (B,H,U)  [exp2 domain]
    const float* __restrict__ MS,      // (B,H,2)
    const float* __restrict__ ctx,     // (B,H,512) = (B,2048)
    const float* __restrict__ Wout,    // (2048,512)
    const float* __restrict__ bout,    // (512)
    float* __restrict__ attw,          // (B,U)
    float* __restrict__ outv)          // (B,512) zeroed by prep
{
    const int b = blockIdx.x;
    const int role = blockIdx.y;
    const int tid = threadIdx.x;

    if (role < 16) {
        // attention_weights = mean_h softmax(energy)
        const int u = role * 256 + tid;
        float acc = 0.f;
        #pragma unroll
        for (int h = 0; h < H; ++h) {
            const float M  = MS[(b * H + h) * 2];
            const float iS = 1.0f / MS[(b * H + h) * 2 + 1];
            acc += fast_exp2(energy[((size_t)b * H + h) * U + u] - M) * iS;
        }
        attw[(size_t)b * U + u] = acc * 0.25f;
    } else {
        // outv[b, jh*256 + tid] += sum over k-chunk of ctx*Wout
        const int idx = role - 16;
        const int jh  = idx & 1;
        const int kc  = idx >> 1;           // 0..7
        const int j   = jh * 256 + tid;
        const int i0  = kc * 256;
        __shared__ float c_s[256];
        c_s[tid] = ctx[(size_t)b * (H * D) + i0 + tid];
        __syncthreads();

        float acc = (kc == 0) ? bout[j] : 0.f;
        #pragma unroll 8
        for (int i = 0; i < 256; ++i)
            acc += c_s[i] * Wout[(size_t)(i0 + i) * AU + j];
        atomicAdd(&outv[(size_t)b * AU + j], acc);
    }
}

extern "C" void kernel_launch(void* const* d_in, const int* in_sizes, int n_in,
                              void* d_out, int out_size, void* d_ws, size_t ws_size,
                              hipStream_t stream) {
    const float* dec   = (const float*)d_in[0];
    const float* enc   = (const float*)d_in[1];
    const float* prevw = (const float*)d_in[2];
    const float* Wphi  = (const float*)d_in[3];
    const float* bphi  = (const float*)d_in[4];
    const float* Wpsi  = (const float*)d_in[5];
    const float* bpsi  = (const float*)d_in[6];
    const float* convk = (const float*)d_in[7];
    const float* Wloc  = (const float*)d_in[8];
    const float* Wout  = (const float*)d_in[9];
    const float* bout  = (const float*)d_in[10];

    float* out  = (float*)d_out;
    float* outv = out;            // (B,512) context_vector
    float* attw = out + B * AU;   // (B,U) attention_weights

    float* ws        = (float*)d_ws;
    float* ws_v      = ws;                        // 65536
    float* ws_const  = ws + 65536;                // 128
    float* ws_ck     = ws + 65664;                // 124 (pad to 65792)
    float* ws_energy = ws + 65792;                // B*H*U = 524288
    float* ws_pctx   = ws_energy + (size_t)B*H*U;            // 2097152
    float* ws_pms    = ws_pctx + (size_t)B*BPB*H*D;          // 8192
    float* ws_MS     = ws_pms + (size_t)B*BPB*H*2;           // 256
    float* ws_ctx    = ws_MS + 256;                          // 65536

    prep_kernel<<<dim3(B * H), 256, 0, stream>>>(dec, Wphi, bphi, Wpsi, bpsi,
                                                 convk, Wloc, ws_v, ws_const,
                                                 ws_ck, outv);
    fused_pass1<<<dim3(BPB, B), 256, 0, stream>>>(enc, prevw, ws_v, ws_const,
                                                  ws_ck, ws_energy, ws_pctx, ws_pms);
    combine_kernel<<<dim3(B * H), 256, 0, stream>>>(ws_pctx, ws_pms, ws_ctx, ws_MS);
    tail_kernel<<<dim3(B, 32), 256, 0, stream>>>(ws_energy, ws_MS, ws_ctx,
                                                 Wout, bout, attw, outv);
}

// Round 6
// 416.872 us; speedup vs baseline: 1.3827x; 1.0307x over previous
//
#include <hip/hip_runtime.h>
#include <math.h>

#define B  32
#define U  4096
#define D  512     // D_DEC == D_ENC
#define H  4
#define HD 128
#define CK 31
#define CF 32
#define AU 512

#define BPB    32           // block-partials per batch row (U / 128 rows-per-block)
#define ROWS_W 32           // u-rows per wave

#define LOG2E 1.4426950408889634f

static __device__ __forceinline__ float readlane_f(float v, int l) {
    return __int_as_float(__builtin_amdgcn_readlane(__float_as_int(v), l));
}
static __device__ __forceinline__ float fast_exp2(float x) {
    return __builtin_amdgcn_exp2f(x);   // bare v_exp_f32 (2^x)
}

// ---------------- Kernel A: phi_s, v = Wpsi @ phi_s, ck = conv (x) Wloc ----
// ws_v / ws_const / ws_ck are pre-scaled by log2(e) so every softmax
// exponential downstream is a bare v_exp_f32 (2^x). softmax is exactly
// invariant: exp(x-m) == 2^((x-m)*log2e).
// Also zeroes outv (replaces a hipMemsetAsync dispatch).
__global__ __launch_bounds__(256) void prep_kernel(
    const float* __restrict__ dec,    // (B,512)
    const float* __restrict__ Wphi,   // (H,512,128)
    const float* __restrict__ bphi,   // (H,128)
    const float* __restrict__ Wpsi,   // (H,512,128)
    const float* __restrict__ bpsi,   // (H,128)
    const float* __restrict__ convk,  // (31,1,32)
    const float* __restrict__ Wloc,   // (32,4)
    float* __restrict__ ws_v,         // (B,H,512)   [scaled by log2e]
    float* __restrict__ ws_const,     // (B,H)       [scaled by log2e]
    float* __restrict__ ws_ck,        // (31,4)      [scaled by log2e]
    float* __restrict__ outv)         // (B,512) -> zeroed here
{
    __shared__ float decs[D];
    __shared__ float ph8[8][HD];      // 4 KB d-group partials
    __shared__ float phis[HD];
    const int b = blockIdx.x / H, h = blockIdx.x % H;
    const int tid = threadIdx.x;

    // zero outv slice for this (b,h)
    if (tid < 128) outv[(size_t)b * AU + h * 128 + tid] = 0.f;

    for (int i = tid; i < D; i += 256) decs[i] = dec[b * D + i];
    __syncthreads();

    // phi projection, float4 over k, 8 d-lanes in parallel:
    // thread = (dg in [0,8)) x (kq/4 in [0,32)); 64 float4 loads/thread.
    {
        const int kq = (tid & 31) * 4;   // k base
        const int dg = tid >> 5;         // d group 0..7
        float4 acc = {0.f, 0.f, 0.f, 0.f};
        const float* wp = Wphi + (size_t)h * D * HD + (size_t)dg * HD + kq;
        #pragma unroll 8
        for (int d0 = 0; d0 < D; d0 += 8) {
            float dv = decs[d0 + dg];
            float4 w = *(const float4*)(wp + (size_t)d0 * HD);
            acc.x += dv * w.x; acc.y += dv * w.y;
            acc.z += dv * w.z; acc.w += dv * w.w;
        }
        *(float4*)&ph8[dg][kq] = acc;
    }
    __syncthreads();
    if (tid < HD) {
        float s = ph8[0][tid] + ph8[1][tid] + ph8[2][tid] + ph8[3][tid]
                + ph8[4][tid] + ph8[5][tid] + ph8[6][tid] + ph8[7][tid]
                + bphi[h * HD + tid];
        phis[tid] = s;
    }
    __syncthreads();

    if (tid == 0) {
        float c = 0.f;
        for (int k = 0; k < HD; ++k) c += phis[k] * bpsi[h * HD + k];
        ws_const[b * H + h] = c * LOG2E;
    }

    // psi projection, float4-vectorized weight loads (16 B/lane)
    for (int e = tid; e < D; e += 256) {
        const float4* wq = (const float4*)(Wpsi + ((size_t)h * D + e) * HD);
        float acc = 0.f;
        #pragma unroll 8
        for (int k = 0; k < HD / 4; ++k) {
            float4 w = wq[k];
            acc += w.x * phis[4*k] + w.y * phis[4*k+1]
                 + w.z * phis[4*k+2] + w.w * phis[4*k+3];
        }
        ws_v[((size_t)b * H + h) * D + e] = acc * LOG2E;
    }

    if (blockIdx.x == 0 && tid < CK * H) {
        int t = tid / H, hh = tid % H;
        float acc = 0.f;
        for (int f = 0; f < CF; ++f) acc += convk[t * CF + f] * Wloc[f * H + hh];
        ws_ck[t * H + hh] = acc * LOG2E;
    }
}

// ---- Pass 1 (fused): energy + online-softmax partial context, ONE enc read
// Block handles 128 u-rows (4 waves x 32); waves merge partials in LDS ->
// ONE (m,s,ctx) partial per block.
// REGISTER-PRESSURE NOTE (round-3 lesson): the loop's live set is ~110 VGPRs
// and __launch_bounds__(256,4) caps at 128. Round 3's folded-combine tail
// flipped the allocator to 64 VGPRs + spills -> pass1 went 3-6x slower
// (272us, VALUBusy 11%, HBM 7%). Do NOT add body code or prefetch depth
// here; 1-row lookahead measured identical to 2-row (BW-bound, not
// latency-starved). THIS KERNEL IS UNCHANGED FROM THE 429.7us MEASUREMENT.
__global__ __launch_bounds__(256, 4) void fused_pass1(
    const float* __restrict__ enc,     // (B,U,512)
    const float* __restrict__ prevw,   // (B,U)
    const float* __restrict__ ws_v,    // (B,H,512)
    const float* __restrict__ ws_const,// (B,H)
    const float* __restrict__ ws_ck,   // (31,4)
    float* __restrict__ energy,        // (B,H,U)  [exp2 domain]
    float* __restrict__ pctx,          // (B,BPB,H,512)
    float* __restrict__ pms)           // (B,BPB,H,2)  m,s  [exp2 domain]
{
    const int b    = blockIdx.y;
    const int blk  = blockIdx.x;              // 0..BPB-1
    const int tid  = threadIdx.x;
    const int lane = tid & 63;
    const int wave = tid >> 6;
    const int ubase = (blk * 4 + wave) * ROWS_W;

    __shared__ float lctx[4][H][D];   // 32 KB
    __shared__ float lms[4][H][2];
    __shared__ float lalpha[H][4];

    // v fragments: lane owns d = lane*4..lane*4+3 and 256+lane*4..+3
    float4 v0[H], v1[H];
    #pragma unroll
    for (int h = 0; h < H; ++h) {
        const float* vp = ws_v + ((size_t)b * H + h) * D;
        v0[h] = *(const float4*)(vp + lane * 4);
        v1[h] = *(const float4*)(vp + 256 + lane * 4);
    }
    float ckr[H] = {0.f, 0.f, 0.f, 0.f};
    if (lane < CK) {
        #pragma unroll
        for (int h = 0; h < H; ++h) ckr[h] = ws_ck[lane * H + h];
    }
    float ct[H];
    #pragma unroll
    for (int h = 0; h < H; ++h) ct[h] = ws_const[b * H + h];

    // prevw window preload: row r, lane l needs prevw[ubase + r + l - 15],
    // and r + l <= 62 < 64, so one 64-lane register covers the whole strip.
    float w0;
    {
        const int gi = ubase - 15 + lane;
        w0 = (gi >= 0 && gi < U) ? prevw[b * U + gi] : 0.f;
    }

    float m0 = -3.402823466e38f, m1 = m0, m2 = m0, m3 = m0;
    float s0 = 0.f, s1 = 0.f, s2 = 0.f, s3 = 0.f;
    float4 z = {0.f, 0.f, 0.f, 0.f};
    float4 c00 = z, c01 = z, c10 = z, c11 = z, c20 = z, c21 = z, c30 = z, c31 = z;

    const bool b16 = (lane & 16) != 0;
    const bool b32 = (lane & 32) != 0;

    const float* encb = enc + ((size_t)b * U + ubase) * D;
    float4 e0 = *(const float4*)(encb + lane * 4);
    float4 e1 = *(const float4*)(encb + 256 + lane * 4);

    for (int r = 0; r < ROWS_W; ++r) {
        float4 n0, n1;
        if (r < ROWS_W - 1) {
            const float* nx = encb + (size_t)(r + 1) * D;
            n0 = *(const float4*)(nx + lane * 4);
            n1 = *(const float4*)(nx + 256 + lane * 4);
        }
        const int u = ubase + r;
        // conv window value via cross-lane pull (no per-row global load)
        float pw = __int_as_float(
            __builtin_amdgcn_ds_bpermute((r + lane) << 2, __float_as_int(w0)));

        float p0 = pw * ckr[0]
            + e0.x*v0[0].x + e0.y*v0[0].y + e0.z*v0[0].z + e0.w*v0[0].w
            + e1.x*v1[0].x + e1.y*v1[0].y + e1.z*v1[0].z + e1.w*v1[0].w;
        float p1 = pw * ckr[1]
            + e0.x*v0[1].x + e0.y*v0[1].y + e0.z*v0[1].z + e0.w*v0[1].w
            + e1.x*v1[1].x + e1.y*v1[1].y + e1.z*v1[1].z + e1.w*v1[1].w;
        float p2 = pw * ckr[2]
            + e0.x*v0[2].x + e0.y*v0[2].y + e0.z*v0[2].z + e0.w*v0[2].w
            + e1.x*v1[2].x + e1.y*v1[2].y + e1.z*v1[2].z + e1.w*v1[2].w;
        float p3 = pw * ckr[3]
            + e0.x*v0[3].x + e0.y*v0[3].y + e0.z*v0[3].z + e0.w*v0[3].w
            + e1.x*v1[3].x + e1.y*v1[3].y + e1.z*v1[3].z + e1.w*v1[3].w;

        // ---- pairwise exchange reduce: group g of 16 lanes ends with head g
        float keepA = b16 ? p1 : p0, sendA = b16 ? p0 : p1;
        float a  = keepA + __shfl_xor(sendA, 16);
        float keepB = b16 ? p3 : p2, sendB = b16 ? p2 : p3;
        float bb = keepB + __shfl_xor(sendB, 16);
        float keepC = b32 ? bb : a, sendC = b32 ? a : bb;
        float c = keepC + __shfl_xor(sendC, 32);
        c += __shfl_xor(c, 1);
        c += __shfl_xor(c, 2);
        c += __shfl_xor(c, 4);
        c += __shfl_xor(c, 8);
        // wave-uniform broadcast via readlane (SGPR-resident)
        float eh0 = readlane_f(c, 0)  + ct[0];
        float eh1 = readlane_f(c, 16) + ct[1];
        float eh2 = readlane_f(c, 32) + ct[2];
        float eh3 = readlane_f(c, 48) + ct[3];

        if (lane < H) {
            float ev = (lane == 0) ? eh0 : (lane == 1) ? eh1 : (lane == 2) ? eh2 : eh3;
            energy[((size_t)b * H + lane) * U + u] = ev;
        }

        // ---- online softmax update (wave-uniform branch), exp2 domain ----
        float mn0 = fmaxf(m0, eh0), mn1 = fmaxf(m1, eh1);
        float mn2 = fmaxf(m2, eh2), mn3 = fmaxf(m3, eh3);
        if (mn0 > m0 || mn1 > m1 || mn2 > m2 || mn3 > m3) {
            float a0 = fast_exp2(m0 - mn0), a1 = fast_exp2(m1 - mn1);
            float a2 = fast_exp2(m2 - mn2), a3 = fast_exp2(m3 - mn3);
            s0 *= a0; s1 *= a1; s2 *= a2; s3 *= a3;
            c00.x*=a0; c00.y*=a0; c00.z*=a0; c00.w*=a0; c01.x*=a0; c01.y*=a0; c01.z*=a0; c01.w*=a0;
            c10.x*=a1; c10.y*=a1; c10.z*=a1; c10.w*=a1; c11.x*=a1; c11.y*=a1; c11.z*=a1; c11.w*=a1;
            c20.x*=a2; c20.y*=a2; c20.z*=a2; c20.w*=a2; c21.x*=a2; c21.y*=a2; c21.z*=a2; c21.w*=a2;
            c30.x*=a3; c30.y*=a3; c30.z*=a3; c30.w*=a3; c31.x*=a3; c31.y*=a3; c31.z*=a3; c31.w*=a3;
            m0 = mn0; m1 = mn1; m2 = mn2; m3 = mn3;
        }
        float w0e = fast_exp2(eh0 - m0), w1e = fast_exp2(eh1 - m1);
        float w2e = fast_exp2(eh2 - m2), w3e = fast_exp2(eh3 - m3);
        s0 += w0e; s1 += w1e; s2 += w2e; s3 += w3e;
        c00.x += w0e*e0.x; c00.y += w0e*e0.y; c00.z += w0e*e0.z; c00.w += w0e*e0.w;
        c01.x += w0e*e1.x; c01.y += w0e*e1.y; c01.z += w0e*e1.z; c01.w += w0e*e1.w;
        c10.x += w1e*e0.x; c10.y += w1e*e0.y; c10.z += w1e*e0.z; c10.w += w1e*e0.w;
        c11.x += w1e*e1.x; c11.y += w1e*e1.y; c11.z += w1e*e1.z; c11.w += w1e*e1.w;
        c20.x += w2e*e0.x; c20.y += w2e*e0.y; c20.z += w2e*e0.z; c20.w += w2e*e0.w;
        c21.x += w2e*e1.x; c21.y += w2e*e1.y; c21.z += w2e*e1.z; c21.w += w2e*e1.w;
        c30.x += w3e*e0.x; c30.y += w3e*e0.y; c30.z += w3e*e0.z; c30.w += w3e*e0.w;
        c31.x += w3e*e1.x; c31.y += w3e*e1.y; c31.z += w3e*e1.z; c31.w += w3e*e1.w;

        e0 = n0; e1 = n1;
    }

    // ---- block-level merge of the 4 wave partials via LDS ----
    *(float4*)&lctx[wave][0][lane * 4]       = c00;
    *(float4*)&lctx[wave][0][256 + lane * 4] = c01;
    *(float4*)&lctx[wave][1][lane * 4]       = c10;
    *(float4*)&lctx[wave][1][256 + lane * 4] = c11;
    *(float4*)&lctx[wave][2][lane * 4]       = c20;
    *(float4*)&lctx[wave][2][256 + lane * 4] = c21;
    *(float4*)&lctx[wave][3][lane * 4]       = c30;
    *(float4*)&lctx[wave][3][256 + lane * 4] = c31;
    if (lane == 0) {
        lms[wave][0][0] = m0; lms[wave][0][1] = s0;
        lms[wave][1][0] = m1; lms[wave][1][1] = s1;
        lms[wave][2][0] = m2; lms[wave][2][1] = s2;
        lms[wave][3][0] = m3; lms[wave][3][1] = s3;
    }
    __syncthreads();

    const size_t pbase = ((size_t)(b * BPB + blk)) * H;
    if (tid < H) {
        const int h = tid;
        float M = fmaxf(fmaxf(lms[0][h][0], lms[1][h][0]),
                        fmaxf(lms[2][h][0], lms[3][h][0]));
        float S = 0.f;
        #pragma unroll
        for (int w = 0; w < 4; ++w) {
            float al = fast_exp2(lms[w][h][0] - M);
            lalpha[h][w] = al;
            S += al * lms[w][h][1];
        }
        pms[(pbase + h) * 2]     = M;
        pms[(pbase + h) * 2 + 1] = S;
    }
    __syncthreads();

    #pragma unroll
    for (int h = 0; h < H; ++h) {
        const float a0 = lalpha[h][0], a1 = lalpha[h][1];
        const float a2 = lalpha[h][2], a3 = lalpha[h][3];
        #pragma unroll
        for (int half = 0; half < 2; ++half) {
            const int d = tid + half * 256;
            float val = a0 * lctx[0][h][d] + a1 * lctx[1][h][d]
                      + a2 * lctx[2][h][d] + a3 * lctx[3][h][d];
            pctx[(pbase + h) * D + d] = val;
        }
    }
}

// ---- Tail (combine folded in via cheap recompute): attw + outproj --------
// grid (B, 32): role in [0,16) -> attw chunk (recomputes M,S from pms: 256
// floats + 32-wide reduce, trivial); role in [16,32) -> outproj slice,
// recomputing its 256-long ctx slice from pctx (32 KB read + 8K FMA) --
// removes the separate combine kernel, its launch gap, and the ctx
// HBM round-trip for +8 MB of redundant L2-resident pctx reads.
__global__ __launch_bounds__(256) void tail_kernel(
    const float* __restrict__ energy,  // (B,H,U)  [exp2 domain]
    const float* __restrict__ pms,     // (B,BPB,H,2)
    const float* __restrict__ pctx,    // (B,BPB,H,512)
    const float* __restrict__ Wout,    // (2048,512)
    const float* __restrict__ bout,    // (512)
    float* __restrict__ attw,          // (B,U)
    float* __restrict__ outv)          // (B,512) zeroed by prep
{
    const int b = blockIdx.x;
    const int role = blockIdx.y;
    const int tid = threadIdx.x;

    if (role < 16) {
        // attention_weights = mean_h softmax(energy); M,S recomputed locally
        __shared__ float lsm[H][BPB], lss[H][BPB];
        __shared__ float lM[H], liS[H];
        if (tid < 128) {
            const int k = tid >> 2, h = tid & 3;
            lsm[h][k] = pms[(((size_t)b * BPB + k) * H + h) * 2];
            lss[h][k] = pms[(((size_t)b * BPB + k) * H + h) * 2 + 1];
        }
        __syncthreads();
        if (tid < H) {
            float M = -3.402823466e38f;
            for (int i = 0; i < BPB; ++i) M = fmaxf(M, lsm[tid][i]);
            float S = 0.f;
            for (int i = 0; i < BPB; ++i)
                S += fast_exp2(lsm[tid][i] - M) * lss[tid][i];
            lM[tid] = M; liS[tid] = 1.0f / S;
        }
        __syncthreads();

        const int u = role * 256 + tid;
        float acc = 0.f;
        #pragma unroll
        for (int h = 0; h < H; ++h)
            acc += fast_exp2(energy[((size_t)b * H + h) * U + u] - lM[h]) * liS[h];
        attw[(size_t)b * U + u] = acc * 0.25f;
    } else {
        // outproj: K-chunk kc covers flattened i = kc*256 .. +255 of (h,e);
        // h = kc>>1, e0 = (kc&1)*256. Recompute ctx slice from pctx.
        const int idx = role - 16;
        const int jh  = idx & 1;
        const int kc  = idx >> 1;           // 0..7
        const int h   = kc >> 1;
        const int e0  = (kc & 1) * 256;
        const int j   = jh * 256 + tid;

        __shared__ float lsm2[BPB], lss2[BPB], sal[BPB];
        __shared__ float sinv;
        __shared__ float c_s[256];

        if (tid < BPB) {
            lsm2[tid] = pms[(((size_t)b * BPB + tid) * H + h) * 2];
            lss2[tid] = pms[(((size_t)b * BPB + tid) * H + h) * 2 + 1];
        }
        __syncthreads();
        if (tid == 0) {
            float M = -3.402823466e38f;
            for (int i = 0; i < BPB; ++i) M = fmaxf(M, lsm2[i]);
            float S = 0.f;
            for (int i = 0; i < BPB; ++i) {
                float al = fast_exp2(lsm2[i] - M);
                sal[i] = al;
                S += al * lss2[i];
            }
            sinv = 1.0f / S;
        }
        __syncthreads();

        // ctx slice: c_s[t] = invS * sum_k sal[k] * pctx[b,k,h,e0+t]
        float acc = 0.f;
        const float* pp = pctx + (((size_t)b * BPB) * H + h) * D + e0 + tid;
        #pragma unroll 8
        for (int k = 0; k < BPB; ++k) acc += sal[k] * pp[(size_t)k * H * D];
        c_s[tid] = acc * sinv;
        __syncthreads();

        float o = (kc == 0) ? bout[j] : 0.f;
        #pragma unroll 8
        for (int i = 0; i < 256; ++i)
            o += c_s[i] * Wout[(size_t)(kc * 256 + i) * AU + j];
        atomicAdd(&outv[(size_t)b * AU + j], o);
    }
}

extern "C" void kernel_launch(void* const* d_in, const int* in_sizes, int n_in,
                              void* d_out, int out_size, void* d_ws, size_t ws_size,
                              hipStream_t stream) {
    const float* dec   = (const float*)d_in[0];
    const float* enc   = (const float*)d_in[1];
    const float* prevw = (const float*)d_in[2];
    const float* Wphi  = (const float*)d_in[3];
    const float* bphi  = (const float*)d_in[4];
    const float* Wpsi  = (const float*)d_in[5];
    const float* bpsi  = (const float*)d_in[6];
    const float* convk = (const float*)d_in[7];
    const float* Wloc  = (const float*)d_in[8];
    const float* Wout  = (const float*)d_in[9];
    const float* bout  = (const float*)d_in[10];

    float* out  = (float*)d_out;
    float* outv = out;            // (B,512) context_vector
    float* attw = out + B * AU;   // (B,U) attention_weights

    float* ws        = (float*)d_ws;
    float* ws_v      = ws;                        // 65536
    float* ws_const  = ws + 65536;                // 128
    float* ws_ck     = ws + 65664;                // 124 (pad to 65792)
    float* ws_energy = ws + 65792;                // B*H*U = 524288
    float* ws_pctx   = ws_energy + (size_t)B*H*U;            // 2097152
    float* ws_pms    = ws_pctx + (size_t)B*BPB*H*D;          // 8192

    prep_kernel<<<dim3(B * H), 256, 0, stream>>>(dec, Wphi, bphi, Wpsi, bpsi,
                                                 convk, Wloc, ws_v, ws_const,
                                                 ws_ck, outv);
    fused_pass1<<<dim3(BPB, B), 256, 0, stream>>>(enc, prevw, ws_v, ws_const,
                                                  ws_ck, ws_energy, ws_pctx, ws_pms);
    tail_kernel<<<dim3(B, 32), 256, 0, stream>>>(ws_energy, ws_pms, ws_pctx,
                                                 Wout, bout, attw, outv);
}